// Round 11
// baseline (253.043 us; speedup 1.0000x reference)
//
#include <hip/hip_runtime.h>
#include <hip/hip_bf16.h>
#include <stdint.h>

// MoTEmbed: out[t,:] = W_{type(t)} @ h[t,:] + b_{type(t)}
// B=4, S=4096 -> T=16384 tokens, D=2048. fp32 in/out, bf16 MFMA compute.
// Round 11: 2-blocks/CU restructure. BM=256 BN=128, 8 waves (4Mx2N),
// acc 4x4 (64 regs, launch_bounds(512,4) caps unified regs at 128),
// 48KB LDS (4 single-buffered sections, section-rotation staging),
// counted vmcnt(1) drains. Cross-block TLP fills the LDS/MFMA serialization
// that capped R7-R10 at ~55% in-block (1 block/CU).

#define T_TOK 16384
#define DDIM  2048
#define NT_K  32           // K tiles of 64
#define MT    64           // M tiles of 256
#define NTIL  16           // N tiles of 128

typedef __attribute__((ext_vector_type(4))) float          f32x4;
typedef __attribute__((ext_vector_type(8))) short          bf16x8;
typedef __attribute__((ext_vector_type(2))) unsigned int   u32x2;

// ---- ws layout (bytes) ----
#define WS_HBF   0ull
#define WS_W0BF  67108864ull                 // 16384*2048*2
#define WS_W1BF  75497472ull                 // + 2048*2048*2
#define WS_META  83886080ull                 // + 2048*2048*2
#define WS_IDX   83886208ull
#define WS_NEED  (WS_IDX + 65536ull)
// meta: [0]=c0 [1]=unused [2]=cur0 [3]=cur1

__device__ __forceinline__ unsigned short cvt1_bf16(float f) {
  unsigned u = __builtin_bit_cast(unsigned, f);
  unsigned rnd = 0x7fffu + ((u >> 16) & 1u);
  return (unsigned short)((u + rnd) >> 16);
}

__device__ __forceinline__ void gload_lds16(const void* g, void* l) {
  __builtin_amdgcn_global_load_lds(
      (const __attribute__((address_space(1))) unsigned int*)g,
      (__attribute__((address_space(3))) unsigned int*)l, 16, 0, 0);
}

#define BAR()    asm volatile("s_barrier" ::: "memory")
#define VMCNT1() asm volatile("s_waitcnt vmcnt(1)" ::: "memory")
#define VMCNT0() asm volatile("s_waitcnt vmcnt(0)" ::: "memory")
#define LGKM0()  asm volatile("s_waitcnt lgkmcnt(0)" ::: "memory")

// ---------- prep: fused convert(H,W0,W1)+count ----------
__global__ void k_prep(const float* __restrict__ H, const float* __restrict__ W0,
                       const float* __restrict__ W1, const int* __restrict__ typ,
                       unsigned short* __restrict__ Hbf,
                       unsigned short* __restrict__ W0bf,
                       unsigned short* __restrict__ W1bf,
                       int* __restrict__ meta) {
  const int gid = blockIdx.x * blockDim.x + threadIdx.x;
  if (gid < T_TOK && typ[gid] == 0) atomicAdd(&meta[0], 1);
  const int nH = T_TOK * DDIM / 4;
  const int nW = DDIM * DDIM / 4;
  const int total = nH + 2 * nW;
  const int stride = gridDim.x * blockDim.x;
  for (int i = gid; i < total; i += stride) {
    const float* s; unsigned short* d; int j;
    if (i < nH)           { s = H;  d = Hbf;  j = i; }
    else if (i < nH + nW) { s = W0; d = W0bf; j = i - nH; }
    else                  { s = W1; d = W1bf; j = i - nH - nW; }
    f32x4 v = ((const f32x4*)s)[j];
    unsigned p0 = (unsigned)cvt1_bf16(v[0]) | ((unsigned)cvt1_bf16(v[1]) << 16);
    unsigned p1 = (unsigned)cvt1_bf16(v[2]) | ((unsigned)cvt1_bf16(v[3]) << 16);
    u32x2 o; o[0] = p0; o[1] = p1;
    ((u32x2*)d)[j] = o;
  }
}

__global__ void k_scatter(const int* __restrict__ typ, int* __restrict__ meta,
                          int* __restrict__ idx) {
  int i = blockIdx.x * blockDim.x + threadIdx.x;
  if (i >= T_TOK) return;
  int c0 = meta[0];                    // final (k_prep completed)
  int t = typ[i];
  int pos = (t == 0) ? atomicAdd(&meta[2], 1) : c0 + atomicAdd(&meta[3], 1);
  idx[pos] = i;
}

// ---------- 256x128 GEMM, 48KB LDS, 2 blocks/CU ----------
// Sections: A0 @0 (16K, 256r x 64B), A1 @16384, B0 @32768 (8K, 128r), B1 @40960.
// Swizzle (R7-verified, conflicts==0): (row, slot s) stored at slot
// s ^ ((row>>1)&3); write via pre-swizzled global slot cs=(lane&3)^((lane>>3)&3);
// read slot = g ^ ((fr>>1)&3).
// Phase actions during tile t (each phase: reads; stage; [vmcnt]; BAR; lgkm0;
// MFMA; BAR):
//   P1: read A0(t)[m0-1]+B0(t)[n0-3]; stage A1(t)    (A1(t-1) certified P4(t-1))
//   P2: read A0(t)[m2-3];             stage B0(t+1)  (B0(t) certified P1 BAR)
//       vmcnt(1) retires {B1(t),A1(t)} -> P3-safe
//   P3: read A1(t)[m0-1]+B1(t)[n0-3]; stage A0(t+1)  (A0(t) certified P2 BAR)
//   P4: read A1(t)[m2-3];             stage B1(t+1)  (B1(t) certified P3 BAR)
//       vmcnt(1) retires {B0(t+1),A0(t+1)} -> next-P1-safe
// Loads/tile/thread: 2+1+2+1=6; outstanding at each drain = 4 -> vmcnt(1).
// Stage->consume distance >= 2 phases; never vmcnt(0) in loop.
__global__ __launch_bounds__(512, 4) void k_gemm(
    const unsigned short* __restrict__ Hbf,
    const unsigned short* __restrict__ W0bf,
    const unsigned short* __restrict__ W1bf,
    const float* __restrict__ B0, const float* __restrict__ B1,
    const int* __restrict__ meta, const int* __restrict__ idx,
    float* __restrict__ OUT)
{
  __shared__ char lds[49152];

  // bijective XCD swizzle: nwg=1024, chunk=128
  const int orig = blockIdx.x;
  const int wg = (orig & 7) * 128 + (orig >> 3);
  int my = wg >> 4;                    // 0..63
  const int bx = wg & 15;              // 0..15

  const int c0 = meta[0];
  int ms = c0 >> 8; if (ms > MT - 1) ms = MT - 1;
  my = (my == 0) ? ms : (my == ms) ? 0 : my;   // straddle tile first

  const int tid  = threadIdx.x;
  const int lane = tid & 63;
  const int wid  = tid >> 6;           // 0..7
  const int wr   = wid >> 1;           // 0..3 (M quarter, 64 rows)
  const int wc   = wid & 1;            // 0..1 (N half, 64 cols)
  const int fr   = lane & 15;
  const int g    = lane >> 4;

  const int start = my * 256;
  const int e0    = (start >= c0) ? 1 : 0;
  const int e1    = (start < c0 && c0 < start + 256) ? 1 : e0;
  const int colBase = bx * 128;

  // staging sources; pre-swizzled global slot (linear LDS dest)
  const int cs = (lane & 3) ^ ((lane >> 3) & 3);
  const char* aS[2];
#pragma unroll
  for (int l = 0; l < 2; ++l) {
    int r_tile = (2 * wid + l) * 16 + (lane >> 2);
    int orow = idx[start + r_tile];
    aS[l] = (const char*)Hbf + (size_t)orow * 4096 + cs * 16;
  }
  const int rb = wid * 16 + (lane >> 2);      // B row 0..127
  const int chA = (2 * wid) * 1024;           // A chunk base (wave-uniform)
  const int chBb = wid * 1024;                // B chunk base

  // fragment byte offsets within a section (swizzled slot)
  const int sw = (g ^ ((fr >> 1) & 3)) << 4;
  int aF[4], bF[4];
#pragma unroll
  for (int m = 0; m < 4; ++m) aF[m] = ((wr * 64 + m * 16 + fr) << 6) + sw;
#pragma unroll
  for (int n = 0; n < 4; ++n) bF[n] = ((wc * 64 + n * 16 + fr) << 6) + sw;

  char* const A0s = lds;
  char* const A1s = lds + 16384;
  char* const B0s = lds + 32768;
  char* const B1s = lds + 40960;

  for (int e = e0; e <= e1; ++e) {
    const unsigned short* Wb = e ? W1bf : W0bf;
    const char* wS = (const char*)(Wb + (size_t)(colBase + rb) * DDIM) + cs * 16;

    f32x4 acc[4][4];
#pragma unroll
    for (int m = 0; m < 4; ++m)
#pragma unroll
      for (int n = 0; n < 4; ++n) acc[m][n] = (f32x4)0.0f;

    auto STAGE_A = [&](int kh, int tn) {
      char* dst = lds + (kh << 14) + chA;
      int ko = tn * 128 + kh * 64;
      gload_lds16(aS[0] + ko, dst);
      gload_lds16(aS[1] + ko, dst + 1024);
    };
    auto STAGE_B = [&](int kh, int tn) {
      char* dst = lds + 32768 + (kh << 13) + chBb;
      gload_lds16(wS + tn * 128 + kh * 64, dst);
    };

    // pass boundary: drain stale stages before re-staging
    VMCNT0();
    BAR();

    // prologue FIFO: [A0(0)x2, B0(0), B1(0)] -> vmcnt(1) retires A0(0),B0(0)
    STAGE_A(0, 0); STAGE_B(0, 0); STAGE_B(1, 0);
    VMCNT1();
    BAR();

#pragma unroll 2
    for (int t = 0; t < NT_K; ++t) {
      int t1 = t + 1; if (t1 == NT_K) t1 = NT_K - 1;   // clamp keeps census exact
      bf16x8 a0, a1, a2, a3, b[4];

      // ---- P1: A0 m0-1 + B0 all; stage A1(t) ----
      a0 = *(const bf16x8*)(A0s + aF[0]);
      a1 = *(const bf16x8*)(A0s + aF[1]);
#pragma unroll
      for (int n = 0; n < 4; ++n) b[n] = *(const bf16x8*)(B0s + bF[n]);
      STAGE_A(1, t);
      BAR(); LGKM0();
      __builtin_amdgcn_s_setprio(1);
#pragma unroll
      for (int n = 0; n < 4; ++n) {
        acc[0][n] = __builtin_amdgcn_mfma_f32_16x16x32_bf16(a0, b[n], acc[0][n], 0, 0, 0);
        acc[1][n] = __builtin_amdgcn_mfma_f32_16x16x32_bf16(a1, b[n], acc[1][n], 0, 0, 0);
      }
      __builtin_amdgcn_s_setprio(0);
      BAR();

      // ---- P2: A0 m2-3 (b reused); stage B0(t+1); drain {B1(t),A1(t)} ----
      a2 = *(const bf16x8*)(A0s + aF[2]);
      a3 = *(const bf16x8*)(A0s + aF[3]);
      STAGE_B(0, t1);
      VMCNT1();
      BAR(); LGKM0();
      __builtin_amdgcn_s_setprio(1);
#pragma unroll
      for (int n = 0; n < 4; ++n) {
        acc[2][n] = __builtin_amdgcn_mfma_f32_16x16x32_bf16(a2, b[n], acc[2][n], 0, 0, 0);
        acc[3][n] = __builtin_amdgcn_mfma_f32_16x16x32_bf16(a3, b[n], acc[3][n], 0, 0, 0);
      }
      __builtin_amdgcn_s_setprio(0);
      BAR();

      // ---- P3: A1 m0-1 + B1 all; stage A0(t+1) ----
      a0 = *(const bf16x8*)(A1s + aF[0]);
      a1 = *(const bf16x8*)(A1s + aF[1]);
#pragma unroll
      for (int n = 0; n < 4; ++n) b[n] = *(const bf16x8*)(B1s + bF[n]);
      STAGE_A(0, t1);
      BAR(); LGKM0();
      __builtin_amdgcn_s_setprio(1);
#pragma unroll
      for (int n = 0; n < 4; ++n) {
        acc[0][n] = __builtin_amdgcn_mfma_f32_16x16x32_bf16(a0, b[n], acc[0][n], 0, 0, 0);
        acc[1][n] = __builtin_amdgcn_mfma_f32_16x16x32_bf16(a1, b[n], acc[1][n], 0, 0, 0);
      }
      __builtin_amdgcn_s_setprio(0);
      BAR();

      // ---- P4: A1 m2-3 (b reused); stage B1(t+1); drain {B0(t+1),A0(t+1)} ----
      a2 = *(const bf16x8*)(A1s + aF[2]);
      a3 = *(const bf16x8*)(A1s + aF[3]);
      STAGE_B(1, t1);
      VMCNT1();
      BAR(); LGKM0();
      __builtin_amdgcn_s_setprio(1);
#pragma unroll
      for (int n = 0; n < 4; ++n) {
        acc[2][n] = __builtin_amdgcn_mfma_f32_16x16x32_bf16(a2, b[n], acc[2][n], 0, 0, 0);
        acc[3][n] = __builtin_amdgcn_mfma_f32_16x16x32_bf16(a3, b[n], acc[3][n], 0, 0, 0);
      }
      __builtin_amdgcn_s_setprio(0);
      BAR();
    }

    VMCNT0();   // endpgm/pass hygiene (loads are >=1 phase old)

    // ---- epilogue: bias + per-row expert predicate + scatter ----
    const float* Bv = e ? B1 : B0;
    float bias[4];
    int cols[4];
#pragma unroll
    for (int n = 0; n < 4; ++n) {
      cols[n] = colBase + wc * 64 + n * 16 + fr;
      bias[n] = Bv[cols[n]];
    }
#pragma unroll
    for (int m = 0; m < 4; ++m) {
      int lb = wr * 64 + m * 16 + (g << 2);
#pragma unroll
      for (int j = 0; j < 4; ++j) {
        int p = start + lb + j;
        if (((p >= c0) ? 1 : 0) != e) continue;
        int orow = idx[p];
        float* op = OUT + (size_t)orow * DDIM;
#pragma unroll
        for (int n = 0; n < 4; ++n) op[cols[n]] = acc[m][n][j] + bias[n];
      }
    }
  }
}

// ---------- fallback: verified round-4 kernel ----------
#define BMd 64
#define BNd 64
#define BKd 32
#define LDW 36

__device__ __forceinline__ bf16x8 cvt_bf16x8(f32x4 lo, f32x4 hi) {
  bf16x8 r;
#pragma unroll
  for (int i = 0; i < 4; ++i) {
    r[i]     = (short)cvt1_bf16(lo[i]);
    r[i + 4] = (short)cvt1_bf16(hi[i]);
  }
  return r;
}

__global__ __launch_bounds__(256, 2) void mot_mfma_diag(
    const float* __restrict__ H,  const int* __restrict__ TYP,
    const float* __restrict__ W0, const float* __restrict__ B0,
    const float* __restrict__ W1, const float* __restrict__ B1,
    float* __restrict__ OUT)
{
  __shared__ float As[BMd * LDW];
  __shared__ float W0s[BNd * LDW];
  __shared__ float W1s[BNd * LDW];

  const int tid = threadIdx.x;
  const int rowBase = blockIdx.y * BMd;
  const int colBase = blockIdx.x * BNd;
  const int srow  = tid >> 3;
  const int scol4 = (tid & 7) << 2;
  const float* hA  = H  + (size_t)(rowBase + srow) * DDIM + scol4;
  const float* hW0 = W0 + (size_t)(colBase + srow) * DDIM + scol4;
  const float* hW1 = W1 + (size_t)(colBase + srow) * DDIM + scol4;

  const int lane = tid & 63;
  const int w    = tid >> 6;
  const int fr   = lane & 15;
  const int g    = lane >> 4;

  f32x4 acc0[4], acc1[4];
#pragma unroll
  for (int m = 0; m < 4; ++m) { acc0[m] = (f32x4)0.0f; acc1[m] = (f32x4)0.0f; }

  for (int k0 = 0; k0 < DDIM; k0 += BKd) {
    f32x4 va[2], v0[2], v1[2];
#pragma unroll
    for (int p = 0; p < 2; ++p) {
      va[p] = *(const f32x4*)(hA  + (size_t)p * 32 * DDIM);
      v0[p] = *(const f32x4*)(hW0 + (size_t)p * 32 * DDIM);
      v1[p] = *(const f32x4*)(hW1 + (size_t)p * 32 * DDIM);
    }
    hA += BKd; hW0 += BKd; hW1 += BKd;
    __syncthreads();
#pragma unroll
    for (int p = 0; p < 2; ++p) {
      int r = srow + 32 * p;
      *(f32x4*)(&As [r * LDW + scol4]) = va[p];
      *(f32x4*)(&W0s[r * LDW + scol4]) = v0[p];
      *(f32x4*)(&W1s[r * LDW + scol4]) = v1[p];
    }
    __syncthreads();

    bf16x8 af[4];
#pragma unroll
    for (int m = 0; m < 4; ++m) {
      const float* ap = &As[(m * 16 + fr) * LDW + g * 8];
      af[m] = cvt_bf16x8(*(const f32x4*)ap, *(const f32x4*)(ap + 4));
    }
    const float* b0p = &W0s[(w * 16 + fr) * LDW + g * 8];
    const float* b1p = &W1s[(w * 16 + fr) * LDW + g * 8];
    bf16x8 bf0 = cvt_bf16x8(*(const f32x4*)b0p, *(const f32x4*)(b0p + 4));
    bf16x8 bf1 = cvt_bf16x8(*(const f32x4*)b1p, *(const f32x4*)(b1p + 4));
#pragma unroll
    for (int m = 0; m < 4; ++m) {
      acc0[m] = __builtin_amdgcn_mfma_f32_16x16x32_bf16(af[m], bf0, acc0[m], 0, 0, 0);
      acc1[m] = __builtin_amdgcn_mfma_f32_16x16x32_bf16(af[m], bf1, acc1[m], 0, 0, 0);
    }
  }

  const int col = colBase + w * 16 + fr;
  const float bz0 = B0[col];
  const float bz1 = B1[col];
#pragma unroll
  for (int m = 0; m < 4; ++m)
#pragma unroll
    for (int j = 0; j < 4; ++j) {
      int row = rowBase + m * 16 + (g << 2) + j;
      int t = TYP[row];
      OUT[(size_t)row * DDIM + col] = (t == 0) ? (acc0[m][j] + bz0) : (acc1[m][j] + bz1);
    }
}

extern "C" void kernel_launch(void* const* d_in, const int* in_sizes, int n_in,
                              void* d_out, int out_size, void* d_ws, size_t ws_size,
                              hipStream_t stream) {
  const float* H   = (const float*)d_in[0];
  const int*   TYP = (const int*)  d_in[1];
  const float* W0  = (const float*)d_in[2];
  const float* B0v = (const float*)d_in[3];
  const float* W1  = (const float*)d_in[4];
  const float* B1v = (const float*)d_in[5];
  float* OUT = (float*)d_out;

  if (ws_size < WS_NEED) {
    dim3 grid(DDIM / BNd, T_TOK / BMd);
    mot_mfma_diag<<<grid, dim3(256), 0, stream>>>(H, TYP, W0, B0v, W1, B1v, OUT);
    return;
  }

  unsigned short* Hbf  = (unsigned short*)((char*)d_ws + WS_HBF);
  unsigned short* W0bf = (unsigned short*)((char*)d_ws + WS_W0BF);
  unsigned short* W1bf = (unsigned short*)((char*)d_ws + WS_W1BF);
  int* meta = (int*)((char*)d_ws + WS_META);
  int* idx  = (int*)((char*)d_ws + WS_IDX);

  hipMemsetAsync(meta, 0, 16, stream);
  k_prep   <<<4096, 256, 0, stream>>>(H, W0, W1, TYP, Hbf, W0bf, W1bf, meta);
  k_scatter<<<64,   256, 0, stream>>>(TYP, meta, idx);
  k_gemm<<<MT * NTIL, 512, 0, stream>>>(Hbf, W0bf, W1bf, B0v, B1v, meta, idx, OUT);
}